// Round 1
// baseline (561.006 us; speedup 1.0000x reference)
//
#include <hip/hip_runtime.h>
#include <stdint.h>

#define DIM_C   2048
#define INNER_C 8192
#define ROWS    8192      // B*L = 4*2048
#define BM 128
#define BN 128
#define BK 64

using bf16x8 = __attribute__((ext_vector_type(8))) __bf16;
using f32x4  = __attribute__((ext_vector_type(4))) float;
using u16x8  = __attribute__((ext_vector_type(8))) unsigned short;

__device__ __forceinline__ unsigned short f2bf(float f) {
  union { float f; unsigned int u; } v; v.f = f;
  unsigned int u = v.u;
  return (unsigned short)((u + 0x7FFFu + ((u >> 16) & 1u)) >> 16);  // RTNE
}

__device__ __forceinline__ void gld_lds16(const void* g, void* l) {
  __builtin_amdgcn_global_load_lds(
      (__attribute__((address_space(1))) void*)(g),
      (__attribute__((address_space(3))) void*)(l), 16, 0, 0);
}

// --- softmax + per-batch truncation width --------------------------------
__global__ void prep_kernel(const float* __restrict__ logits,
                            float* __restrict__ p_out,
                            int* __restrict__ kb) {
  const int b = threadIdx.x;
  if (b < 4) {
    float x0 = logits[b * 4 + 0], x1 = logits[b * 4 + 1];
    float x2 = logits[b * 4 + 2], x3 = logits[b * 4 + 3];
    float m = fmaxf(fmaxf(x0, x1), fmaxf(x2, x3));
    float e0 = __expf(x0 - m), e1 = __expf(x1 - m);
    float e2 = __expf(x2 - m), e3 = __expf(x3 - m);
    float inv = 1.f / (e0 + e1 + e2 + e3);
    p_out[b * 4 + 0] = e0 * inv;
    p_out[b * 4 + 1] = e1 * inv;
    p_out[b * 4 + 2] = e2 * inv;
    p_out[b * 4 + 3] = e3 * inv;
    int idx = 0; float best = x0;                 // first-max, like jnp.argmax
    if (x1 > best) { best = x1; idx = 1; }
    if (x2 > best) { best = x2; idx = 2; }
    if (x3 > best) { best = x3; idx = 3; }
    kb[b] = (idx + 1) * (INNER_C / 4);
  }
}

// --- fp32 -> bf16 bulk convert (8 elems/thread, 16B stores) --------------
__global__ void cvt_kernel(const float* __restrict__ in,
                           unsigned short* __restrict__ out, int n8) {
  int i = blockIdx.x * blockDim.x + threadIdx.x;
  if (i >= n8) return;
  const float4* p = reinterpret_cast<const float4*>(in) + (size_t)i * 2;
  float4 a = p[0], b = p[1];
  u16x8 r;
  r[0] = f2bf(a.x); r[1] = f2bf(a.y); r[2] = f2bf(a.z); r[3] = f2bf(a.w);
  r[4] = f2bf(b.x); r[5] = f2bf(b.y); r[6] = f2bf(b.z); r[7] = f2bf(b.w);
  *(reinterpret_cast<u16x8*>(out) + i) = r;
}

// --- NT bf16 GEMM, m97 structure: 128x128 tile, BK=64, 4 waves -----------
// MODE 0: C = gelu(A*B^T + bias) -> bf16 H, skip col tiles >= kb[batch]
// MODE 1: C = A*B^T + bias -> f32 out, K-loop truncated to kb[batch]
template <int MODE>
__global__ __launch_bounds__(256, 2) void gemm_bt(
    const unsigned short* __restrict__ A,
    const unsigned short* __restrict__ B,
    const float* __restrict__ bias,
    void* __restrict__ C,
    const int* __restrict__ kb_arr) {
  constexpr int KDIM = (MODE == 0) ? DIM_C : INNER_C;  // A/B row stride = K
  __shared__ __align__(16) unsigned short As[BM * BK];
  __shared__ __align__(16) unsigned short Bs[BN * BK];

  const int nt = blockIdx.x;
  const int mt = blockIdx.y;
  const int batch = mt >> 4;                 // 2048/BM = 16 row tiles / batch
  const int kbv = kb_arr[batch];
  if (MODE == 0 && nt * BN >= kbv) return;   // masked columns: never written/read
  const int kTiles = (MODE == 0) ? (KDIM / BK) : (kbv / BK);

  const int tid = threadIdx.x;
  const int wave = tid >> 6;
  const int lane = tid & 63;
  const int wr0 = (wave >> 1) * 64;          // 2x2 wave grid, 64x64 per wave
  const int wc0 = (wave & 1) * 64;
  const int la = lane & 15, lb = lane >> 4;

  const int sRow = lane >> 3;                // staging: 8 rows / 1KB chunk
  const int sCol = (lane & 7) * 8;
  const size_t row0 = (size_t)mt * BM;
  const size_t col0 = (size_t)nt * BN;

  f32x4 acc[4][4];
#pragma unroll
  for (int m = 0; m < 4; ++m)
#pragma unroll
    for (int n = 0; n < 4; ++n) acc[m][n] = (f32x4){0.f, 0.f, 0.f, 0.f};

  for (int kt = 0; kt < kTiles; ++kt) {
    __syncthreads();                         // protect LDS from overwrite
    const size_t kOff = (size_t)kt * BK + sCol;
#pragma unroll
    for (int i = 0; i < 4; ++i) {
      const int q = wave * 4 + i;            // 16 x 1KB chunks per tile
      const int r = q * 8 + sRow;
      gld_lds16(&A[(row0 + r) * KDIM + kOff], &As[q * 512]);
      gld_lds16(&B[(col0 + r) * KDIM + kOff], &Bs[q * 512]);
    }
    __syncthreads();                         // drains vmcnt before barrier
#pragma unroll
    for (int ks = 0; ks < 2; ++ks) {
      bf16x8 af[4], bf[4];
#pragma unroll
      for (int m = 0; m < 4; ++m)
        af[m] = *reinterpret_cast<const bf16x8*>(
            &As[(wr0 + m * 16 + la) * BK + ks * 32 + lb * 8]);
#pragma unroll
      for (int n = 0; n < 4; ++n)
        bf[n] = *reinterpret_cast<const bf16x8*>(
            &Bs[(wc0 + n * 16 + la) * BK + ks * 32 + lb * 8]);
#pragma unroll
      for (int m = 0; m < 4; ++m)
#pragma unroll
        for (int n = 0; n < 4; ++n)
          acc[m][n] = __builtin_amdgcn_mfma_f32_16x16x32_bf16(
              af[m], bf[n], acc[m][n], 0, 0, 0);
    }
  }

  // epilogue: C/D layout col = lane&15, row = (lane>>4)*4 + j  [m89/m91]
#pragma unroll
  for (int m = 0; m < 4; ++m) {
#pragma unroll
    for (int n = 0; n < 4; ++n) {
      const size_t c = col0 + wc0 + n * 16 + la;
      const float bv = bias[c];
#pragma unroll
      for (int j = 0; j < 4; ++j) {
        const size_t r = row0 + wr0 + m * 16 + lb * 4 + j;
        float x = acc[m][n][j] + bv;
        if (MODE == 0) {
          float g = x / (1.f + __expf(-1.702f * x));  // x*sigmoid(1.702x)
          ((unsigned short*)C)[r * (size_t)INNER_C + c] = f2bf(g);
        } else {
          ((float*)C)[r * (size_t)DIM_C + c] = x;
        }
      }
    }
  }
}

extern "C" void kernel_launch(void* const* d_in, const int* in_sizes, int n_in,
                              void* d_out, int out_size, void* d_ws,
                              size_t ws_size, hipStream_t stream) {
  const float* hidden = (const float*)d_in[0];  // [4,2048,2048]
  const float* logitw = (const float*)d_in[1];  // [4,4]
  const float* W1     = (const float*)d_in[2];  // [8192,2048]
  const float* b1     = (const float*)d_in[3];  // [8192]
  const float* W2     = (const float*)d_in[4];  // [2048,8192]
  const float* b2     = (const float*)d_in[5];  // [2048]
  float* out   = (float*)d_out;
  float* p_out = out + (size_t)ROWS * DIM_C;    // tuple tail: p_soft [4,4]

  char* ws = (char*)d_ws;
  int*            kb   = (int*)ws;                                    // 16 B
  unsigned short* Abf  = (unsigned short*)(ws + 256);                 // 32 MiB
  unsigned short* W1bf = (unsigned short*)(ws + 256 + 33554432);      // 32 MiB
  unsigned short* W2bf = (unsigned short*)(ws + 256 + 2 * 33554432);  // 32 MiB
  unsigned short* Hbf  = (unsigned short*)(ws + 256 + 3 * 33554432);  // 128 MiB

  prep_kernel<<<1, 64, 0, stream>>>(logitw, p_out, kb);

  const int n8 = 16777216 / 8;  // each of A/W1/W2 is 16.7M fp32
  cvt_kernel<<<n8 / 256, 256, 0, stream>>>(hidden, Abf, n8);
  cvt_kernel<<<n8 / 256, 256, 0, stream>>>(W1, W1bf, n8);
  cvt_kernel<<<n8 / 256, 256, 0, stream>>>(W2, W2bf, n8);

  gemm_bt<0><<<dim3(INNER_C / BN, ROWS / BM), 256, 0, stream>>>(
      Abf, W1bf, b1, Hbf, kb);
  gemm_bt<1><<<dim3(DIM_C / BN, ROWS / BM), 256, 0, stream>>>(
      Hbf, W2bf, b2, out, kb);
}